// Round 6
// baseline (345.243 us; speedup 1.0000x reference)
//
#include <hip/hip_runtime.h>
#include <math.h>

#define NEG_INF -1e30f

// =======================================================================
// qkv_ln: LN folded into A-staging; A stored transposed in As[k&31][k>>5][m].
// grid (4,16,3). z==0&&bx==0 blocks store X := src + bo.
// z==1&&bx==1 blocks zero outb (accumulator for this layer's ff_fused).
// =======================================================================
__global__ __launch_bounds__(256) void qkv_ln_kernel(
    const float* __restrict__ srcin, const float* __restrict__ tgt,
    const float* __restrict__ g1, const float* __restrict__ b1,
    const float* __restrict__ gt, const float* __restrict__ bt,
    const float* __restrict__ bo,
    const float* __restrict__ wq, const float* __restrict__ wk, const float* __restrict__ wv,
    const float* __restrict__ bq, const float* __restrict__ bk, const float* __restrict__ bv,
    float* __restrict__ Qb, float* __restrict__ Kb, float* __restrict__ Vb,
    float* __restrict__ X, float* __restrict__ outb)
{
  __shared__ float As[32][8][36];
  __shared__ float Bs[32][64];
  int z = blockIdx.z;
  int m0 = blockIdx.y * 32, n0 = blockIdx.x * 64;
  const float* Bw   = (z == 0) ? wq : (z == 1) ? wk : wv;
  const float* bias = (z == 0) ? bq : (z == 1) ? bk : bv;
  const float* g    = (z == 0) ? g1 : gt;
  const float* be   = (z == 0) ? b1 : bt;
  int tid = threadIdx.x;
  int r = tid >> 3, c8 = tid & 7;
  int row = m0 + r;
  const float* arow = ((z == 0) ? srcin : tgt) + (size_t)row * 256 + c8 * 32;

  float4 x[8];
  float s = 0, ss = 0;
#pragma unroll
  for (int j = 0; j < 8; ++j) {
    x[j] = ((const float4*)arow)[j];
    s  += x[j].x + x[j].y + x[j].z + x[j].w;
    ss += x[j].x*x[j].x + x[j].y*x[j].y + x[j].z*x[j].z + x[j].w*x[j].w;
  }
#pragma unroll
  for (int off = 1; off < 8; off <<= 1) {
    s  += __shfl_xor(s,  off);
    ss += __shfl_xor(ss, off);
  }
  float mean = s * (1.0f / 256.0f);
  float var  = ss * (1.0f / 256.0f) - mean * mean;
  float rstd = rsqrtf(var + 1e-5f);
#pragma unroll
  for (int j = 0; j < 8; ++j) {
    float4 gg = ((const float4*)(g  + c8 * 32))[j];
    float4 bb = ((const float4*)(be + c8 * 32))[j];
    As[j*4+0][c8][r] = (x[j].x - mean) * rstd * gg.x + bb.x;
    As[j*4+1][c8][r] = (x[j].y - mean) * rstd * gg.y + bb.y;
    As[j*4+2][c8][r] = (x[j].z - mean) * rstd * gg.z + bb.z;
    As[j*4+3][c8][r] = (x[j].w - mean) * rstd * gg.w + bb.w;
  }
  if (z == 0 && blockIdx.x == 0) {          // X := src + bo
#pragma unroll
    for (int j = 0; j < 8; ++j) {
      float4 bo4 = ((const float4*)(bo + c8 * 32))[j];
      float4 xi;
      xi.x = x[j].x + bo4.x; xi.y = x[j].y + bo4.y;
      xi.z = x[j].z + bo4.z; xi.w = x[j].w + bo4.w;
      *(float4*)&X[(size_t)row * 256 + c8 * 32 + j * 4] = xi;
    }
  }
  if (z == 1 && blockIdx.x == 1) {          // outb := 0 (ff_fused accumulator)
    float4 zz = {};
#pragma unroll
    for (int j = 0; j < 8; ++j)
      *(float4*)&outb[(size_t)row * 256 + c8 * 32 + j * 4] = zz;
  }
  __syncthreads();

  int tx = tid & 15, ty = tid >> 4;
  float acc[2][4] = {};
  for (int kc = 0; kc < 256; kc += 32) {
    const float* bp = Bw + (size_t)(kc + r) * 256 + n0;
    float4 b0  = *(const float4*)(bp + c8 * 4);
    float4 b1v = *(const float4*)(bp + 32 + c8 * 4);
    *(float4*)&Bs[r][c8 * 4]      = b0;
    *(float4*)&Bs[r][32 + c8 * 4] = b1v;
    __syncthreads();
    int kcc = kc >> 5;
#pragma unroll
    for (int kk = 0; kk < 32; ++kk) {
      float2 av = *(const float2*)&As[kk][kcc][ty * 2];
      float4 bv = *(const float4*)&Bs[kk][tx * 4];
      acc[0][0] = fmaf(av.x, bv.x, acc[0][0]); acc[0][1] = fmaf(av.x, bv.y, acc[0][1]);
      acc[0][2] = fmaf(av.x, bv.z, acc[0][2]); acc[0][3] = fmaf(av.x, bv.w, acc[0][3]);
      acc[1][0] = fmaf(av.y, bv.x, acc[1][0]); acc[1][1] = fmaf(av.y, bv.y, acc[1][1]);
      acc[1][2] = fmaf(av.y, bv.z, acc[1][2]); acc[1][3] = fmaf(av.y, bv.w, acc[1][3]);
    }
    __syncthreads();
  }

  int c0 = n0 + tx * 4;
  const float scale = 0.1767766952966369f;   // 1/sqrt(32)
#pragma unroll
  for (int i = 0; i < 2; ++i) {
    int m = m0 + ty * 2 + i;
    float4 rr;
    rr.x = acc[i][0] + bias[c0 + 0];
    rr.y = acc[i][1] + bias[c0 + 1];
    rr.z = acc[i][2] + bias[c0 + 2];
    rr.w = acc[i][3] + bias[c0 + 3];
    if (z == 0) {
      rr.x *= scale; rr.y *= scale; rr.z *= scale; rr.w *= scale;
      *(float4*)&Qb[m * 256 + c0] = rr;
    } else {
      int b = m >> 8, t = m & 255, h = c0 >> 5, d0 = c0 & 31;
      float* dst = ((z == 1) ? Kb : Vb) + (size_t)(b * 8 + h) * 8192 + t * 32 + d0;
      *(float4*)dst = rr;
    }
  }
}

// =======================================================================
// attn_wo: attention for (b,h,16 s-rows) + fused wo split-K epilogue:
// X[s,:] += O_tile[16x32] @ wo[h*32:+32, :]  (X pre-init src+bo).
// Ks LDS (32KB) is reused as the wo-slice buffer in phase 2.
// =======================================================================
__global__ __launch_bounds__(256) void attn_wo_kernel(
    const float* __restrict__ Qb, const float* __restrict__ Kb, const float* __restrict__ Vb,
    const float* __restrict__ rpe, const int* __restrict__ tmask,
    const float* __restrict__ wrl, const float* __restrict__ brl,
    const float* __restrict__ wo_l,
    float* __restrict__ X)
{
  __shared__ float KsW[8192];     // Ks[256][32] phase1 | wos[32][256] phase2
  __shared__ float Vt[32][260];
  __shared__ float ps[4][256];
  __shared__ float qs[16][32];
  __shared__ float wks[5][32];
  __shared__ float wvs[5][32];
  __shared__ float Os[16][32];
  float (*Ks)[32]  = (float (*)[32])KsW;
  float (*wos)[256] = (float (*)[256])KsW;

  int bid = blockIdx.x;
  int b = bid >> 7, h = (bid >> 4) & 7, s0 = (bid & 15) << 4;
  int tid = threadIdx.x;
  const float* Kp = Kb + (size_t)(b * 8 + h) * 8192;
  const float* Vp = Vb + (size_t)(b * 8 + h) * 8192;
  {
    int t = tid;
    const float4* kr = (const float4*)(Kp + t * 32);
    const float4* vr = (const float4*)(Vp + t * 32);
    int sw = t & 7;
#pragma unroll
    for (int c = 0; c < 8; ++c) {
      float4 k4 = kr[c];
      *(float4*)&Ks[t][(c ^ sw) * 4] = k4;
    }
#pragma unroll
    for (int c = 0; c < 8; ++c) {
      float4 v4 = vr[c];
      Vt[c*4+0][t] = v4.x; Vt[c*4+1][t] = v4.y; Vt[c*4+2][t] = v4.z; Vt[c*4+3][t] = v4.w;
    }
  }
  if (tid < 160) {
    int j = tid >> 5, d = tid & 31;
    wks[j][d] = (j < 4) ? wrl[j * 512 + h * 32 + d]       : brl[h * 32 + d];
    wvs[j][d] = (j < 4) ? wrl[j * 512 + 256 + h * 32 + d] : brl[256 + h * 32 + d];
  }
  if (tid >= 128) {
    int u = tid - 128;
    int rr2 = u >> 3, cc = u & 7;
    *(float4*)&qs[rr2][cc*4] =
        *(const float4*)&Qb[(b * 256 + s0 + rr2) * 256 + h * 32 + cc * 4];
  }
  __syncthreads();

  int w = tid >> 6, lane = tid & 63;
  int msk[4];
#pragma unroll
  for (int it = 0; it < 4; ++it) msk[it] = tmask[b * 256 + it * 64 + lane];

  for (int i = 0; i < 4; ++i) {
    int sl = w * 4 + i;
    int s = s0 + sl;
    float4 q4[8];
#pragma unroll
    for (int c = 0; c < 8; ++c) q4[c] = *(const float4*)&qs[sl][c * 4];
    float qw[4]; float qbr = 0.0f;
#pragma unroll
    for (int j = 0; j < 4; ++j) {
      float t0 = 0;
#pragma unroll
      for (int c = 0; c < 8; ++c) {
        float4 wv4 = *(const float4*)&wks[j][c * 4];
        t0 += q4[c].x*wv4.x + q4[c].y*wv4.y + q4[c].z*wv4.z + q4[c].w*wv4.w;
      }
      qw[j] = t0;
    }
#pragma unroll
    for (int c = 0; c < 8; ++c) {
      float4 wv4 = *(const float4*)&wks[4][c * 4];
      qbr += q4[c].x*wv4.x + q4[c].y*wv4.y + q4[c].z*wv4.z + q4[c].w*wv4.w;
    }
    const float4* rp4 = (const float4*)(rpe + (size_t)(b * 256 + s) * 1024);
    float sc[4]; float4 rr[4];
#pragma unroll
    for (int it = 0; it < 4; ++it) {
      int t = it * 64 + lane;
      int sw = t & 7;
      float sv = 0;
#pragma unroll
      for (int c = 0; c < 8; ++c) {
        float4 k4 = *(const float4*)&Ks[t][(c ^ sw) * 4];
        sv = fmaf(q4[c].x, k4.x, sv); sv = fmaf(q4[c].y, k4.y, sv);
        sv = fmaf(q4[c].z, k4.z, sv); sv = fmaf(q4[c].w, k4.w, sv);
      }
      float4 rv = rp4[t];
      rr[it] = rv;
      sv += rv.x*qw[0] + rv.y*qw[1] + rv.z*qw[2] + rv.w*qw[3] + qbr;
      if (msk[it] != 0) sv = NEG_INF;
      sc[it] = sv;
    }
    float mval = fmaxf(fmaxf(sc[0], sc[1]), fmaxf(sc[2], sc[3]));
#pragma unroll
    for (int off = 32; off >= 1; off >>= 1) mval = fmaxf(mval, __shfl_xor(mval, off));
    float p[4], lsum = 0;
#pragma unroll
    for (int it = 0; it < 4; ++it) { p[it] = __expf(sc[it] - mval); lsum += p[it]; }
    float wj0 = 0, wj1 = 0, wj2 = 0, wj3 = 0;
#pragma unroll
    for (int it = 0; it < 4; ++it) {
      wj0 = fmaf(p[it], rr[it].x, wj0);
      wj1 = fmaf(p[it], rr[it].y, wj1);
      wj2 = fmaf(p[it], rr[it].z, wj2);
      wj3 = fmaf(p[it], rr[it].w, wj3);
    }
#pragma unroll
    for (int off = 32; off >= 1; off >>= 1) {
      lsum += __shfl_xor(lsum, off);
      wj0 += __shfl_xor(wj0, off);
      wj1 += __shfl_xor(wj1, off);
      wj2 += __shfl_xor(wj2, off);
      wj3 += __shfl_xor(wj3, off);
    }
#pragma unroll
    for (int it = 0; it < 4; ++it) ps[w][it * 64 + lane] = p[it];
    int g = lane >> 5, d = lane & 31;
    float o = 0;
#pragma unroll
    for (int n = 0; n < 32; ++n) {
      int t = g * 128 + n * 4;
      float4 p4 = *(const float4*)&ps[w][t];
      float4 v4 = *(const float4*)&Vt[d][t];
      o += p4.x*v4.x + p4.y*v4.y + p4.z*v4.z + p4.w*v4.w;
    }
    o += __shfl_xor(o, 32);
    float corr = wj0 * wvs[0][d] + wj1 * wvs[1][d] + wj2 * wvs[2][d] + wj3 * wvs[3][d];
    float oval = (o + corr) / lsum + wvs[4][d];
    if (lane < 32) Os[sl][d] = oval;
  }
  __syncthreads();                           // all Ks reads + Os writes done

  // ---- phase 2: X[s0..s0+16, :] += Os[16x32] @ wo[h*32:+32, 0:256] ----
  {
    int k = tid >> 3, c8 = tid & 7;
    const float4* sw = (const float4*)(wo_l + (size_t)(h * 32 + k) * 256 + c8 * 32);
    float4* dst = (float4*)&wos[k][c8 * 32];
#pragma unroll
    for (int j = 0; j < 8; ++j) dst[j] = sw[j];
  }
  __syncthreads();
  {
    int col = lane * 4, r0 = w * 4;
    float4 acc[4] = {};
    for (int kk = 0; kk < 8; ++kk) {
      float4 w0  = *(const float4*)&wos[kk*4+0][col];
      float4 w1v = *(const float4*)&wos[kk*4+1][col];
      float4 w2v = *(const float4*)&wos[kk*4+2][col];
      float4 w3v = *(const float4*)&wos[kk*4+3][col];
#pragma unroll
      for (int r = 0; r < 4; ++r) {
        float4 o4 = *(const float4*)&Os[r0 + r][kk * 4];
        acc[r].x += o4.x*w0.x + o4.y*w1v.x + o4.z*w2v.x + o4.w*w3v.x;
        acc[r].y += o4.x*w0.y + o4.y*w1v.y + o4.z*w2v.y + o4.w*w3v.y;
        acc[r].z += o4.x*w0.z + o4.y*w1v.z + o4.z*w2v.z + o4.w*w3v.z;
        acc[r].w += o4.x*w0.w + o4.y*w1v.w + o4.z*w2v.w + o4.w*w3v.w;
      }
    }
#pragma unroll
    for (int r = 0; r < 4; ++r) {
      float* xp = &X[(size_t)(b * 256 + s0 + r0 + r) * 256 + col];
      atomicAdd(xp + 0, acc[r].x);
      atomicAdd(xp + 1, acc[r].y);
      atomicAdd(xp + 2, acc[r].z);
      atomicAdd(xp + 3, acc[r].w);
    }
  }
}

// =======================================================================
// ff_fused: LN2 folded A-staging -> ff1 (32x64 H tile, ReLU, kept in LDS)
// -> fused ff2 split-K epilogue: outb += mask * (Htile @ w2[n0:+64, :]).
// bx==0 blocks also add mask*(X + b2). outb pre-zeroed by qkv_ln.
// =======================================================================
__global__ __launch_bounds__(256) void ff_fused_kernel(
    const float* __restrict__ Xin,
    const float* __restrict__ g2, const float* __restrict__ be2,
    const float* __restrict__ b2, const int* __restrict__ smask,
    const float* __restrict__ w1, const float* __restrict__ b1,
    const float* __restrict__ w2,
    float* __restrict__ outb)
{
  __shared__ float AsW[9216];   // As[k&31][k>>5][m] (stride 36) | w2s[32][256]
  __shared__ float BsH[2048];   // Bs[32][64] (ff1 B) | Hs[32][64] (relu tile)
  float (*w2s)[256] = (float (*)[256])AsW;
  float (*Bs)[64] = (float (*)[64])BsH;
  float (*Hs)[64] = (float (*)[64])BsH;
#define AS(k,c,m) AsW[((k) * 8 + (c)) * 36 + (m)]
  int m0 = blockIdx.y * 32, n0 = blockIdx.x * 64;
  int tid = threadIdx.x;
  int r = tid >> 3, c8 = tid & 7;
  int row = m0 + r;
  const float* arow = Xin + (size_t)row * 256 + c8 * 32;

  float4 x[8];
  float s = 0, ss = 0;
#pragma unroll
  for (int j = 0; j < 8; ++j) {
    x[j] = ((const float4*)arow)[j];
    s  += x[j].x + x[j].y + x[j].z + x[j].w;
    ss += x[j].x*x[j].x + x[j].y*x[j].y + x[j].z*x[j].z + x[j].w*x[j].w;
  }
#pragma unroll
  for (int off = 1; off < 8; off <<= 1) {
    s  += __shfl_xor(s,  off);
    ss += __shfl_xor(ss, off);
  }
  float mean = s * (1.0f / 256.0f);
  float var  = ss * (1.0f / 256.0f) - mean * mean;
  float rstd = rsqrtf(var + 1e-5f);
#pragma unroll
  for (int j = 0; j < 8; ++j) {
    float4 gg = ((const float4*)(g2  + c8 * 32))[j];
    float4 bb = ((const float4*)(be2 + c8 * 32))[j];
    AS(j*4+0, c8, r) = (x[j].x - mean) * rstd * gg.x + bb.x;
    AS(j*4+1, c8, r) = (x[j].y - mean) * rstd * gg.y + bb.y;
    AS(j*4+2, c8, r) = (x[j].z - mean) * rstd * gg.z + bb.z;
    AS(j*4+3, c8, r) = (x[j].w - mean) * rstd * gg.w + bb.w;
  }
  __syncthreads();

  int tx = tid & 15, ty = tid >> 4;
  float acc[2][4] = {};
  for (int kc = 0; kc < 256; kc += 32) {
    const float* bp = w1 + (size_t)(kc + r) * 1024 + n0;
    float4 b0  = *(const float4*)(bp + c8 * 4);
    float4 b1v = *(const float4*)(bp + 32 + c8 * 4);
    *(float4*)&Bs[r][c8 * 4]      = b0;
    *(float4*)&Bs[r][32 + c8 * 4] = b1v;
    __syncthreads();
    int kcc = kc >> 5;
#pragma unroll
    for (int kk = 0; kk < 32; ++kk) {
      float2 av = *(const float2*)&AS(kk, kcc, ty * 2);
      float4 bv = *(const float4*)&Bs[kk][tx * 4];
      acc[0][0] = fmaf(av.x, bv.x, acc[0][0]); acc[0][1] = fmaf(av.x, bv.y, acc[0][1]);
      acc[0][2] = fmaf(av.x, bv.z, acc[0][2]); acc[0][3] = fmaf(av.x, bv.w, acc[0][3]);
      acc[1][0] = fmaf(av.y, bv.x, acc[1][0]); acc[1][1] = fmaf(av.y, bv.y, acc[1][1]);
      acc[1][2] = fmaf(av.y, bv.z, acc[1][2]); acc[1][3] = fmaf(av.y, bv.w, acc[1][3]);
    }
    __syncthreads();
  }

  // H tile (ReLU) into LDS (aliases Bs — all reads done after last sync)
  {
    int c0 = n0 + tx * 4;
#pragma unroll
    for (int i = 0; i < 2; ++i) {
      int rl = ty * 2 + i;
      Hs[rl][tx*4+0] = fmaxf(acc[i][0] + b1[c0 + 0], 0.0f);
      Hs[rl][tx*4+1] = fmaxf(acc[i][1] + b1[c0 + 1], 0.0f);
      Hs[rl][tx*4+2] = fmaxf(acc[i][2] + b1[c0 + 2], 0.0f);
      Hs[rl][tx*4+3] = fmaxf(acc[i][3] + b1[c0 + 3], 0.0f);
    }
  }

  // ---- fused ff2 partial: outb[m0..+32, :] += mask * Hs @ w2[n0:+64, :] ----
  int lane = tid & 63, w = tid >> 6;
  int col = lane * 4, r0 = w * 8;
  float4 acc2[8] = {};
  for (int half = 0; half < 2; ++half) {
    __syncthreads();   // Hs written (half 0) / previous w2s reads done (half 1)
    {
      int k = tid >> 3;
      const float4* sw = (const float4*)(w2 + (size_t)(n0 + half * 32 + k) * 256 + c8 * 32);
      float4* dst = (float4*)&w2s[k][c8 * 32];
#pragma unroll
      for (int j = 0; j < 8; ++j) dst[j] = sw[j];
    }
    __syncthreads();
    for (int kk = 0; kk < 8; ++kk) {
      float4 w0  = *(const float4*)&w2s[kk*4+0][col];
      float4 w1v = *(const float4*)&w2s[kk*4+1][col];
      float4 w2v = *(const float4*)&w2s[kk*4+2][col];
      float4 w3v = *(const float4*)&w2s[kk*4+3][col];
#pragma unroll
      for (int rr = 0; rr < 8; ++rr) {
        float4 h4 = *(const float4*)&Hs[r0 + rr][half * 32 + kk * 4];
        acc2[rr].x += h4.x*w0.x + h4.y*w1v.x + h4.z*w2v.x + h4.w*w3v.x;
        acc2[rr].y += h4.x*w0.y + h4.y*w1v.y + h4.z*w2v.y + h4.w*w3v.y;
        acc2[rr].z += h4.x*w0.z + h4.y*w1v.z + h4.z*w2v.z + h4.w*w3v.z;
        acc2[rr].w += h4.x*w0.w + h4.y*w1v.w + h4.z*w2v.w + h4.w*w3v.w;
      }
    }
  }
#pragma unroll
  for (int rr = 0; rr < 8; ++rr) {
    int m = m0 + r0 + rr;
    float mm = (smask[m] != 0) ? 0.0f : 1.0f;
    float4 add = acc2[rr];
    if (blockIdx.x == 0) {       // residual + b2 added exactly once
      float4 x4  = *(const float4*)&Xin[(size_t)m * 256 + col];
      float4 b24 = *(const float4*)&b2[col];
      add.x += x4.x + b24.x; add.y += x4.y + b24.y;
      add.z += x4.z + b24.z; add.w += x4.w + b24.w;
    }
    float* op = &outb[(size_t)m * 256 + col];
    atomicAdd(op + 0, mm * add.x);
    atomicAdd(op + 1, mm * add.y);
    atomicAdd(op + 2, mm * add.z);
    atomicAdd(op + 3, mm * add.w);
  }
#undef AS
}

extern "C" void kernel_launch(void* const* d_in, const int* in_sizes, int n_in,
                              void* d_out, int out_size, void* d_ws, size_t ws_size,
                              hipStream_t stream)
{
  const float* src  = (const float*)d_in[0];
  const float* tgt  = (const float*)d_in[1];
  const float* rpe  = (const float*)d_in[2];
  const int*   smask = (const int*)d_in[3];
  const int*   tmask = (const int*)d_in[4];
  const float* ln1g = (const float*)d_in[5];
  const float* ln1b = (const float*)d_in[6];
  const float* lntg = (const float*)d_in[7];
  const float* lntb = (const float*)d_in[8];
  const float* ln2g = (const float*)d_in[9];
  const float* ln2b = (const float*)d_in[10];
  const float* wq = (const float*)d_in[11];
  const float* bq = (const float*)d_in[12];
  const float* wk = (const float*)d_in[13];
  const float* bk = (const float*)d_in[14];
  const float* wv = (const float*)d_in[15];
  const float* bv = (const float*)d_in[16];
  const float* wo = (const float*)d_in[17];
  const float* bo = (const float*)d_in[18];
  const float* wr = (const float*)d_in[19];
  const float* br = (const float*)d_in[20];
  const float* w1 = (const float*)d_in[21];
  const float* b1 = (const float*)d_in[22];
  const float* w2 = (const float*)d_in[23];
  const float* b2 = (const float*)d_in[24];

  float* ws   = (float*)d_ws;
  float* Qb   = ws;
  float* Kb   = ws + 131072;
  float* Vb   = ws + 262144;
  float* X    = ws + 393216;
  float* SRC1 = ws + 524288;

  for (int l = 0; l < 2; ++l) {
    const float* srcin = l ? SRC1 : src;
    float* outb = l ? (float*)d_out : SRC1;
    qkv_ln_kernel<<<dim3(4, 16, 3), 256, 0, stream>>>(
        srcin, tgt, ln1g + l*256, ln1b + l*256, lntg + l*256, lntb + l*256,
        bo + l*256,
        wq + l*65536, wk + l*65536, wv + l*65536,
        bq + l*256, bk + l*256, bv + l*256,
        Qb, Kb, Vb, X, outb);
    attn_wo_kernel<<<256, 256, 0, stream>>>(Qb, Kb, Vb, rpe, tmask,
                                            wr + l*2048, br + l*512,
                                            wo + l*65536, X);
    ff_fused_kernel<<<dim3(16, 16), 256, 0, stream>>>(
        X, ln2g + l*256, ln2b + l*256, b2 + l*256, smask,
        w1 + l*262144, b1 + l*1024, w2 + l*262144, outb);
  }
}

// Round 7
// 274.235 us; speedup vs baseline: 1.2589x; 1.2589x over previous
//
#include <hip/hip_runtime.h>
#include <math.h>

#define NEG_INF -1e30f

// =======================================================================
// qkv_ln: LN folded into A-staging; A stored transposed in As[k&31][k>>5][m].
// 32x32 tiles, grid (8,16,3): n0=bx*32, m0=by*32, z: 0=Q 1=K 2=V.
// z==0&&bx==0 blocks store X := src + bo.
// =======================================================================
__global__ __launch_bounds__(256) void qkv_ln_kernel(
    const float* __restrict__ srcin, const float* __restrict__ tgt,
    const float* __restrict__ g1, const float* __restrict__ b1,
    const float* __restrict__ gt, const float* __restrict__ bt,
    const float* __restrict__ bo,
    const float* __restrict__ wq, const float* __restrict__ wk, const float* __restrict__ wv,
    const float* __restrict__ bq, const float* __restrict__ bk, const float* __restrict__ bv,
    float* __restrict__ Qb, float* __restrict__ Kb, float* __restrict__ Vb,
    float* __restrict__ X)
{
  __shared__ float As[32][8][36];   // [k&31][k>>5][m]
  __shared__ float Bs[32][36];      // padded: conflict-free b64 reads
  int z = blockIdx.z;
  int m0 = blockIdx.y * 32, n0 = blockIdx.x * 32;
  const float* Bw   = (z == 0) ? wq : (z == 1) ? wk : wv;
  const float* bias = (z == 0) ? bq : (z == 1) ? bk : bv;
  const float* g    = (z == 0) ? g1 : gt;
  const float* be   = (z == 0) ? b1 : bt;
  int tid = threadIdx.x;
  int r = tid >> 3, c8 = tid & 7;
  int row = m0 + r;
  const float* arow = ((z == 0) ? srcin : tgt) + (size_t)row * 256 + c8 * 32;

  float4 x[8];
  float s = 0, ss = 0;
#pragma unroll
  for (int j = 0; j < 8; ++j) {
    x[j] = ((const float4*)arow)[j];
    s  += x[j].x + x[j].y + x[j].z + x[j].w;
    ss += x[j].x*x[j].x + x[j].y*x[j].y + x[j].z*x[j].z + x[j].w*x[j].w;
  }
#pragma unroll
  for (int off = 1; off < 8; off <<= 1) {
    s  += __shfl_xor(s,  off);
    ss += __shfl_xor(ss, off);
  }
  float mean = s * (1.0f / 256.0f);
  float var  = ss * (1.0f / 256.0f) - mean * mean;
  float rstd = rsqrtf(var + 1e-5f);
#pragma unroll
  for (int j = 0; j < 8; ++j) {
    float4 gg = ((const float4*)(g  + c8 * 32))[j];
    float4 bb = ((const float4*)(be + c8 * 32))[j];
    As[j*4+0][c8][r] = (x[j].x - mean) * rstd * gg.x + bb.x;
    As[j*4+1][c8][r] = (x[j].y - mean) * rstd * gg.y + bb.y;
    As[j*4+2][c8][r] = (x[j].z - mean) * rstd * gg.z + bb.z;
    As[j*4+3][c8][r] = (x[j].w - mean) * rstd * gg.w + bb.w;
  }
  if (z == 0 && blockIdx.x == 0) {          // X := src + bo
#pragma unroll
    for (int j = 0; j < 8; ++j) {
      float4 bo4 = ((const float4*)(bo + c8 * 32))[j];
      float4 xi;
      xi.x = x[j].x + bo4.x; xi.y = x[j].y + bo4.y;
      xi.z = x[j].z + bo4.z; xi.w = x[j].w + bo4.w;
      *(float4*)&X[(size_t)row * 256 + c8 * 32 + j * 4] = xi;
    }
  }
  __syncthreads();

  int tx = tid & 15, ty = tid >> 4;
  float acc[2][2] = {};
  for (int kc = 0; kc < 256; kc += 32) {
    float4 b0 = *(const float4*)(Bw + (size_t)(kc + r) * 256 + n0 + c8 * 4);
    *(float4*)&Bs[r][c8 * 4] = b0;
    __syncthreads();
    int kcc = kc >> 5;
#pragma unroll
    for (int kk = 0; kk < 32; ++kk) {
      float2 av = *(const float2*)&As[kk][kcc][ty * 2];
      float2 bv = *(const float2*)&Bs[kk][tx * 2];
      acc[0][0] = fmaf(av.x, bv.x, acc[0][0]); acc[0][1] = fmaf(av.x, bv.y, acc[0][1]);
      acc[1][0] = fmaf(av.y, bv.x, acc[1][0]); acc[1][1] = fmaf(av.y, bv.y, acc[1][1]);
    }
    __syncthreads();
  }

  int c0 = n0 + tx * 2;
  const float scale = 0.1767766952966369f;   // 1/sqrt(32)
#pragma unroll
  for (int i = 0; i < 2; ++i) {
    int m = m0 + ty * 2 + i;
    float2 rr;
    rr.x = acc[i][0] + bias[c0 + 0];
    rr.y = acc[i][1] + bias[c0 + 1];
    if (z == 0) {
      rr.x *= scale; rr.y *= scale;
      *(float2*)&Qb[m * 256 + c0] = rr;
    } else {
      int b = m >> 8, t = m & 255, h = c0 >> 5, d0 = c0 & 31;
      float* dst = ((z == 1) ? Kb : Vb) + (size_t)(b * 8 + h) * 8192 + t * 32 + d0;
      *(float2*)dst = rr;
    }
  }
}

// =======================================================================
// ff1_ln2: LN2-folded A-staging -> ff1 + ReLU -> H1. 32x32 tiles,
// grid (32,16). bx==0 blocks store outb := mask*(X + b2)  (ff2 init).
// =======================================================================
__global__ __launch_bounds__(256) void ff1_ln2_kernel(
    const float* __restrict__ Xin,
    const float* __restrict__ g2, const float* __restrict__ be2,
    const float* __restrict__ b2, const int* __restrict__ smask,
    const float* __restrict__ w1, const float* __restrict__ b1,
    float* __restrict__ H1, float* __restrict__ outb)
{
  __shared__ float As[32][8][36];
  __shared__ float Bs[32][36];
  int m0 = blockIdx.y * 32, n0 = blockIdx.x * 32;
  int tid = threadIdx.x;
  int r = tid >> 3, c8 = tid & 7;
  int row = m0 + r;
  const float* arow = Xin + (size_t)row * 256 + c8 * 32;

  float4 x[8];
  float s = 0, ss = 0;
#pragma unroll
  for (int j = 0; j < 8; ++j) {
    x[j] = ((const float4*)arow)[j];
    s  += x[j].x + x[j].y + x[j].z + x[j].w;
    ss += x[j].x*x[j].x + x[j].y*x[j].y + x[j].z*x[j].z + x[j].w*x[j].w;
  }
#pragma unroll
  for (int off = 1; off < 8; off <<= 1) {
    s  += __shfl_xor(s,  off);
    ss += __shfl_xor(ss, off);
  }
  float mean = s * (1.0f / 256.0f);
  float var  = ss * (1.0f / 256.0f) - mean * mean;
  float rstd = rsqrtf(var + 1e-5f);
#pragma unroll
  for (int j = 0; j < 8; ++j) {
    float4 gg = ((const float4*)(g2  + c8 * 32))[j];
    float4 bb = ((const float4*)(be2 + c8 * 32))[j];
    As[j*4+0][c8][r] = (x[j].x - mean) * rstd * gg.x + bb.x;
    As[j*4+1][c8][r] = (x[j].y - mean) * rstd * gg.y + bb.y;
    As[j*4+2][c8][r] = (x[j].z - mean) * rstd * gg.z + bb.z;
    As[j*4+3][c8][r] = (x[j].w - mean) * rstd * gg.w + bb.w;
  }
  if (blockIdx.x == 0) {                    // outb := mask*(X + b2)
    float mm = (smask[row] != 0) ? 0.0f : 1.0f;
#pragma unroll
    for (int j = 0; j < 8; ++j) {
      float4 b24 = ((const float4*)(b2 + c8 * 32))[j];
      float4 oi;
      oi.x = mm * (x[j].x + b24.x); oi.y = mm * (x[j].y + b24.y);
      oi.z = mm * (x[j].z + b24.z); oi.w = mm * (x[j].w + b24.w);
      *(float4*)&outb[(size_t)row * 256 + c8 * 32 + j * 4] = oi;
    }
  }
  __syncthreads();

  int tx = tid & 15, ty = tid >> 4;
  float acc[2][2] = {};
  for (int kc = 0; kc < 256; kc += 32) {
    float4 b0 = *(const float4*)(w1 + (size_t)(kc + r) * 1024 + n0 + c8 * 4);
    *(float4*)&Bs[r][c8 * 4] = b0;
    __syncthreads();
    int kcc = kc >> 5;
#pragma unroll
    for (int kk = 0; kk < 32; ++kk) {
      float2 av = *(const float2*)&As[kk][kcc][ty * 2];
      float2 bv = *(const float2*)&Bs[kk][tx * 2];
      acc[0][0] = fmaf(av.x, bv.x, acc[0][0]); acc[0][1] = fmaf(av.x, bv.y, acc[0][1]);
      acc[1][0] = fmaf(av.y, bv.x, acc[1][0]); acc[1][1] = fmaf(av.y, bv.y, acc[1][1]);
    }
    __syncthreads();
  }

  int c0 = n0 + tx * 2;
#pragma unroll
  for (int i = 0; i < 2; ++i) {
    int m = m0 + ty * 2 + i;
    float2 rr;
    rr.x = fmaxf(acc[i][0] + b1[c0 + 0], 0.0f);
    rr.y = fmaxf(acc[i][1] + b1[c0 + 1], 0.0f);
    *(float2*)&H1[m * 1024 + c0] = rr;
  }
}

// ---------- plain 32x32 GEMM core (A transposed per-kc), for wo/ff2 ----------
__device__ __forceinline__ void gemm_core32x32(
    const float* __restrict__ A, int lda,
    const float* __restrict__ Bw, int ldb,
    int kbeg, int kend, int m0, int n0,
    float acc[2][2])
{
  __shared__ float At[32][36];
  __shared__ float Bs[32][36];
  int tid = threadIdx.x;
  int tx = tid & 15, ty = tid >> 4;
  int r  = tid >> 3, c8 = tid & 7;
  for (int kc = kbeg; kc < kend; kc += 32) {
    float4 a  = *(const float4*)(A  + (size_t)(m0 + r) * lda + kc + c8 * 4);
    float4 b0 = *(const float4*)(Bw + (size_t)(kc + r) * ldb + n0 + c8 * 4);
    At[c8*4+0][r] = a.x; At[c8*4+1][r] = a.y; At[c8*4+2][r] = a.z; At[c8*4+3][r] = a.w;
    *(float4*)&Bs[r][c8 * 4] = b0;
    __syncthreads();
#pragma unroll
    for (int k = 0; k < 32; ++k) {
      float2 av = *(const float2*)&At[k][ty * 2];
      float2 bv = *(const float2*)&Bs[k][tx * 2];
      acc[0][0] = fmaf(av.x, bv.x, acc[0][0]); acc[0][1] = fmaf(av.x, bv.y, acc[0][1]);
      acc[1][0] = fmaf(av.y, bv.x, acc[1][0]); acc[1][1] = fmaf(av.y, bv.y, acc[1][1]);
    }
    __syncthreads();
  }
}

// ---------- wo GEMM split-K=2, 32x32 tiles, atomic into X : grid (8,16,2) ----------
__global__ __launch_bounds__(256) void wo_kernel(
    const float* __restrict__ AO, const float* __restrict__ wo,
    float* __restrict__ X)
{
  int m0 = blockIdx.y * 32, n0 = blockIdx.x * 32;
  int kbeg = blockIdx.z * 128;
  float acc[2][2] = {};
  gemm_core32x32(AO, 256, wo, 256, kbeg, kbeg + 128, m0, n0, acc);
  int tid = threadIdx.x, tx = tid & 15, ty = tid >> 4;
  int c0 = n0 + tx * 2;
#pragma unroll
  for (int i = 0; i < 2; ++i) {
    int m = m0 + ty * 2 + i;
    atomicAdd(&X[m * 256 + c0 + 0], acc[i][0]);
    atomicAdd(&X[m * 256 + c0 + 1], acc[i][1]);
  }
}

// ---------- FF2 split-K=4, 32x32 tiles, masked atomic : grid (8,16,4) ----------
__global__ __launch_bounds__(256) void ff2_kernel(
    const float* __restrict__ H1, const float* __restrict__ w2,
    const int* __restrict__ smask, float* __restrict__ outb)
{
  int m0 = blockIdx.y * 32, n0 = blockIdx.x * 32;
  int kbeg = blockIdx.z * 256;
  float acc[2][2] = {};
  gemm_core32x32(H1, 1024, w2, 256, kbeg, kbeg + 256, m0, n0, acc);
  int tid = threadIdx.x, tx = tid & 15, ty = tid >> 4;
  int c0 = n0 + tx * 2;
#pragma unroll
  for (int i = 0; i < 2; ++i) {
    int m = m0 + ty * 2 + i;
    float mm = (smask[m] != 0) ? 0.0f : 1.0f;
    atomicAdd(&outb[m * 256 + c0 + 0], mm * acc[i][0]);
    atomicAdd(&outb[m * 256 + c0 + 1], mm * acc[i][1]);
  }
}

// ---------- attention: block = (b,h,8 s-rows), 256 thr; grid 512 ----------
__global__ __launch_bounds__(256) void attn_kernel(
    const float* __restrict__ Qb, const float* __restrict__ Kb, const float* __restrict__ Vb,
    const float* __restrict__ rpe, const int* __restrict__ tmask,
    const float* __restrict__ wrl, const float* __restrict__ brl,
    float* __restrict__ AO)
{
  __shared__ float Ks[256][32];
  __shared__ float Vt[32][260];
  __shared__ float ps[4][256];
  __shared__ float qs[8][32];
  __shared__ float wks[5][32];
  __shared__ float wvs[5][32];
  int bid = blockIdx.x;
  int b = bid >> 8, h = (bid >> 5) & 7, s0 = (bid & 31) << 3;
  int tid = threadIdx.x;
  const float* Kp = Kb + (size_t)(b * 8 + h) * 8192;
  const float* Vp = Vb + (size_t)(b * 8 + h) * 8192;
  {
    int t = tid;
    const float4* kr = (const float4*)(Kp + t * 32);
    const float4* vr = (const float4*)(Vp + t * 32);
    int sw = t & 7;
#pragma unroll
    for (int c = 0; c < 8; ++c) {
      float4 k4 = kr[c];
      *(float4*)&Ks[t][(c ^ sw) * 4] = k4;
    }
#pragma unroll
    for (int c = 0; c < 8; ++c) {
      float4 v4 = vr[c];
      Vt[c*4+0][t] = v4.x; Vt[c*4+1][t] = v4.y; Vt[c*4+2][t] = v4.z; Vt[c*4+3][t] = v4.w;
    }
  }
  if (tid < 160) {
    int j = tid >> 5, d = tid & 31;
    wks[j][d] = (j < 4) ? wrl[j * 512 + h * 32 + d]       : brl[h * 32 + d];
    wvs[j][d] = (j < 4) ? wrl[j * 512 + 256 + h * 32 + d] : brl[256 + h * 32 + d];
  }
  if (tid >= 192) {                    // 64 threads load the 8x32 Q tile
    int u = tid - 192;
    int rr2 = u >> 3, cc = u & 7;
    *(float4*)&qs[rr2][cc*4] =
        *(const float4*)&Qb[(b * 256 + s0 + rr2) * 256 + h * 32 + cc * 4];
  }
  __syncthreads();

  int w = tid >> 6, lane = tid & 63;
  int msk[4];
#pragma unroll
  for (int it = 0; it < 4; ++it) msk[it] = tmask[b * 256 + it * 64 + lane];

  for (int i = 0; i < 2; ++i) {
    int sl = w * 2 + i;
    int s = s0 + sl;
    float4 q4[8];
#pragma unroll
    for (int c = 0; c < 8; ++c) q4[c] = *(const float4*)&qs[sl][c * 4];
    float qw[4]; float qbr = 0.0f;
#pragma unroll
    for (int j = 0; j < 4; ++j) {
      float t0 = 0;
#pragma unroll
      for (int c = 0; c < 8; ++c) {
        float4 wv4 = *(const float4*)&wks[j][c * 4];
        t0 += q4[c].x*wv4.x + q4[c].y*wv4.y + q4[c].z*wv4.z + q4[c].w*wv4.w;
      }
      qw[j] = t0;
    }
#pragma unroll
    for (int c = 0; c < 8; ++c) {
      float4 wv4 = *(const float4*)&wks[4][c * 4];
      qbr += q4[c].x*wv4.x + q4[c].y*wv4.y + q4[c].z*wv4.z + q4[c].w*wv4.w;
    }
    const float4* rp4 = (const float4*)(rpe + (size_t)(b * 256 + s) * 1024);
    float sc[4]; float4 rr[4];
#pragma unroll
    for (int it = 0; it < 4; ++it) {
      int t = it * 64 + lane;
      int sw = t & 7;
      float sv = 0;
#pragma unroll
      for (int c = 0; c < 8; ++c) {
        float4 k4 = *(const float4*)&Ks[t][(c ^ sw) * 4];
        sv = fmaf(q4[c].x, k4.x, sv); sv = fmaf(q4[c].y, k4.y, sv);
        sv = fmaf(q4[c].z, k4.z, sv); sv = fmaf(q4[c].w, k4.w, sv);
      }
      float4 rv = rp4[t];
      rr[it] = rv;
      sv += rv.x*qw[0] + rv.y*qw[1] + rv.z*qw[2] + rv.w*qw[3] + qbr;
      if (msk[it] != 0) sv = NEG_INF;
      sc[it] = sv;
    }
    float mval = fmaxf(fmaxf(sc[0], sc[1]), fmaxf(sc[2], sc[3]));
#pragma unroll
    for (int off = 32; off >= 1; off >>= 1) mval = fmaxf(mval, __shfl_xor(mval, off));
    float p[4], lsum = 0;
#pragma unroll
    for (int it = 0; it < 4; ++it) { p[it] = __expf(sc[it] - mval); lsum += p[it]; }
    float wj0 = 0, wj1 = 0, wj2 = 0, wj3 = 0;
#pragma unroll
    for (int it = 0; it < 4; ++it) {
      wj0 = fmaf(p[it], rr[it].x, wj0);
      wj1 = fmaf(p[it], rr[it].y, wj1);
      wj2 = fmaf(p[it], rr[it].z, wj2);
      wj3 = fmaf(p[it], rr[it].w, wj3);
    }
#pragma unroll
    for (int off = 32; off >= 1; off >>= 1) {
      lsum += __shfl_xor(lsum, off);
      wj0 += __shfl_xor(wj0, off);
      wj1 += __shfl_xor(wj1, off);
      wj2 += __shfl_xor(wj2, off);
      wj3 += __shfl_xor(wj3, off);
    }
#pragma unroll
    for (int it = 0; it < 4; ++it) ps[w][it * 64 + lane] = p[it];
    int g = lane >> 5, d = lane & 31;
    float o = 0;
#pragma unroll
    for (int n = 0; n < 32; ++n) {
      int t = g * 128 + n * 4;
      float4 p4 = *(const float4*)&ps[w][t];
      float4 v4 = *(const float4*)&Vt[d][t];
      o += p4.x*v4.x + p4.y*v4.y + p4.z*v4.z + p4.w*v4.w;
    }
    o += __shfl_xor(o, 32);
    float corr = wj0 * wvs[0][d] + wj1 * wvs[1][d] + wj2 * wvs[2][d] + wj3 * wvs[3][d];
    float oval = (o + corr) / lsum + wvs[4][d];
    if (lane < 32) AO[(b * 256 + s) * 256 + h * 32 + d] = oval;
  }
}

extern "C" void kernel_launch(void* const* d_in, const int* in_sizes, int n_in,
                              void* d_out, int out_size, void* d_ws, size_t ws_size,
                              hipStream_t stream)
{
  const float* src  = (const float*)d_in[0];
  const float* tgt  = (const float*)d_in[1];
  const float* rpe  = (const float*)d_in[2];
  const int*   smask = (const int*)d_in[3];
  const int*   tmask = (const int*)d_in[4];
  const float* ln1g = (const float*)d_in[5];
  const float* ln1b = (const float*)d_in[6];
  const float* lntg = (const float*)d_in[7];
  const float* lntb = (const float*)d_in[8];
  const float* ln2g = (const float*)d_in[9];
  const float* ln2b = (const float*)d_in[10];
  const float* wq = (const float*)d_in[11];
  const float* bq = (const float*)d_in[12];
  const float* wk = (const float*)d_in[13];
  const float* bk = (const float*)d_in[14];
  const float* wv = (const float*)d_in[15];
  const float* bv = (const float*)d_in[16];
  const float* wo = (const float*)d_in[17];
  const float* bo = (const float*)d_in[18];
  const float* wr = (const float*)d_in[19];
  const float* br = (const float*)d_in[20];
  const float* w1 = (const float*)d_in[21];
  const float* b1 = (const float*)d_in[22];
  const float* w2 = (const float*)d_in[23];
  const float* b2 = (const float*)d_in[24];

  float* ws   = (float*)d_ws;
  float* Qb   = ws;
  float* Kb   = ws + 131072;
  float* Vb   = ws + 262144;
  float* AO   = ws + 393216;
  float* X    = ws + 524288;
  float* SRC1 = ws + 655360;
  float* H1   = ws + 786432;

  for (int l = 0; l < 2; ++l) {
    const float* srcin = l ? SRC1 : src;
    float* outb = l ? (float*)d_out : SRC1;
    qkv_ln_kernel<<<dim3(8, 16, 3), 256, 0, stream>>>(
        srcin, tgt, ln1g + l*256, ln1b + l*256, lntg + l*256, lntb + l*256,
        bo + l*256,
        wq + l*65536, wk + l*65536, wv + l*65536,
        bq + l*256, bk + l*256, bv + l*256,
        Qb, Kb, Vb, X);
    attn_kernel<<<512, 256, 0, stream>>>(Qb, Kb, Vb, rpe, tmask,
                                         wr + l*2048, br + l*512, AO);
    wo_kernel<<<dim3(8, 16, 2), 256, 0, stream>>>(AO, wo + l*65536, X);
    ff1_ln2_kernel<<<dim3(32, 16), 256, 0, stream>>>(
        X, ln2g + l*256, ln2b + l*256, b2 + l*256, smask,
        w1 + l*262144, b1 + l*1024, H1, outb);
    ff2_kernel<<<dim3(8, 16, 4), 256, 0, stream>>>(H1, w2 + l*262144, smask, outb);
  }
}

// Round 8
// 267.723 us; speedup vs baseline: 1.2896x; 1.0243x over previous
//
#include <hip/hip_runtime.h>
#include <math.h>

#define NEG_INF -1e30f

// =======================================================================
// qkv_ln: LN folded into A-staging (As[k&31][k>>5][m], stride 36); FULL
// B tile (256x32) staged once into Bs[256][34]; single sync; 256-iter
// barrier-free K loop. grid (8,16,3). z==0&&bx==0 stores X := src + bo.
// =======================================================================
__global__ __launch_bounds__(256, 2) void qkv_ln_kernel(
    const float* __restrict__ srcin, const float* __restrict__ tgt,
    const float* __restrict__ g1, const float* __restrict__ b1,
    const float* __restrict__ gt, const float* __restrict__ bt,
    const float* __restrict__ bo,
    const float* __restrict__ wq, const float* __restrict__ wk, const float* __restrict__ wv,
    const float* __restrict__ bq, const float* __restrict__ bk, const float* __restrict__ bv,
    float* __restrict__ Qb, float* __restrict__ Kb, float* __restrict__ Vb,
    float* __restrict__ X)
{
  __shared__ float As[32][8][36];   // 36864 B
  __shared__ float Bs[256][34];     // 34816 B  (total ~71.7 KB -> 2 blocks/CU)
  int z = blockIdx.z;
  int m0 = blockIdx.y * 32, n0 = blockIdx.x * 32;
  const float* Bw   = (z == 0) ? wq : (z == 1) ? wk : wv;
  const float* bias = (z == 0) ? bq : (z == 1) ? bk : bv;
  const float* g    = (z == 0) ? g1 : gt;
  const float* be   = (z == 0) ? b1 : bt;
  int tid = threadIdx.x;
  int r = tid >> 3, c8 = tid & 7;
  int row = m0 + r;
  const float* arow = ((z == 0) ? srcin : tgt) + (size_t)row * 256 + c8 * 32;

  float4 x[8];
  float s = 0, ss = 0;
#pragma unroll
  for (int j = 0; j < 8; ++j) {
    x[j] = ((const float4*)arow)[j];
    s  += x[j].x + x[j].y + x[j].z + x[j].w;
    ss += x[j].x*x[j].x + x[j].y*x[j].y + x[j].z*x[j].z + x[j].w*x[j].w;
  }
#pragma unroll
  for (int off = 1; off < 8; off <<= 1) {
    s  += __shfl_xor(s,  off);
    ss += __shfl_xor(ss, off);
  }
  float mean = s * (1.0f / 256.0f);
  float var  = ss * (1.0f / 256.0f) - mean * mean;
  float rstd = rsqrtf(var + 1e-5f);
#pragma unroll
  for (int j = 0; j < 8; ++j) {
    float4 gg = ((const float4*)(g  + c8 * 32))[j];
    float4 bb = ((const float4*)(be + c8 * 32))[j];
    As[j*4+0][c8][r] = (x[j].x - mean) * rstd * gg.x + bb.x;
    As[j*4+1][c8][r] = (x[j].y - mean) * rstd * gg.y + bb.y;
    As[j*4+2][c8][r] = (x[j].z - mean) * rstd * gg.z + bb.z;
    As[j*4+3][c8][r] = (x[j].w - mean) * rstd * gg.w + bb.w;
  }
  // full B tile: 8 passes, k = kb*32 + r, cols n0 + c8*4
#pragma unroll
  for (int kb = 0; kb < 8; ++kb) {
    int k = kb * 32 + r;
    float4 b4 = *(const float4*)(Bw + (size_t)k * 256 + n0 + c8 * 4);
    *(float4*)&Bs[k][c8 * 4] = b4;
  }
  if (z == 0 && blockIdx.x == 0) {          // X := src + bo
#pragma unroll
    for (int j = 0; j < 8; ++j) {
      float4 bo4 = ((const float4*)(bo + c8 * 32))[j];
      float4 xi;
      xi.x = x[j].x + bo4.x; xi.y = x[j].y + bo4.y;
      xi.z = x[j].z + bo4.z; xi.w = x[j].w + bo4.w;
      *(float4*)&X[(size_t)row * 256 + c8 * 32 + j * 4] = xi;
    }
  }
  __syncthreads();

  int tx = tid & 15, ty = tid >> 4;
  float acc[2][2] = {};
  for (int kcc = 0; kcc < 8; ++kcc) {
#pragma unroll
    for (int kk = 0; kk < 32; ++kk) {
      float2 av = *(const float2*)&As[kk][kcc][ty * 2];
      float2 bv = *(const float2*)&Bs[kcc * 32 + kk][tx * 2];
      acc[0][0] = fmaf(av.x, bv.x, acc[0][0]); acc[0][1] = fmaf(av.x, bv.y, acc[0][1]);
      acc[1][0] = fmaf(av.y, bv.x, acc[1][0]); acc[1][1] = fmaf(av.y, bv.y, acc[1][1]);
    }
  }

  int c0 = n0 + tx * 2;
  const float scale = 0.1767766952966369f;   // 1/sqrt(32)
#pragma unroll
  for (int i = 0; i < 2; ++i) {
    int m = m0 + ty * 2 + i;
    float2 rr;
    rr.x = acc[i][0] + bias[c0 + 0];
    rr.y = acc[i][1] + bias[c0 + 1];
    if (z == 0) {
      rr.x *= scale; rr.y *= scale;
      *(float2*)&Qb[m * 256 + c0] = rr;
    } else {
      int b = m >> 8, t = m & 255, h = c0 >> 5, d0 = c0 & 31;
      float* dst = ((z == 1) ? Kb : Vb) + (size_t)(b * 8 + h) * 8192 + t * 32 + d0;
      *(float2*)dst = rr;
    }
  }
}

// =======================================================================
// ff1_ln2: same full-stage scheme, B from w1 (ldb 1024). grid (32,16).
// bx==0 blocks store outb := mask*(X + b2).
// =======================================================================
__global__ __launch_bounds__(256, 2) void ff1_ln2_kernel(
    const float* __restrict__ Xin,
    const float* __restrict__ g2, const float* __restrict__ be2,
    const float* __restrict__ b2, const int* __restrict__ smask,
    const float* __restrict__ w1, const float* __restrict__ b1,
    float* __restrict__ H1, float* __restrict__ outb)
{
  __shared__ float As[32][8][36];
  __shared__ float Bs[256][34];
  int m0 = blockIdx.y * 32, n0 = blockIdx.x * 32;
  int tid = threadIdx.x;
  int r = tid >> 3, c8 = tid & 7;
  int row = m0 + r;
  const float* arow = Xin + (size_t)row * 256 + c8 * 32;

  float4 x[8];
  float s = 0, ss = 0;
#pragma unroll
  for (int j = 0; j < 8; ++j) {
    x[j] = ((const float4*)arow)[j];
    s  += x[j].x + x[j].y + x[j].z + x[j].w;
    ss += x[j].x*x[j].x + x[j].y*x[j].y + x[j].z*x[j].z + x[j].w*x[j].w;
  }
#pragma unroll
  for (int off = 1; off < 8; off <<= 1) {
    s  += __shfl_xor(s,  off);
    ss += __shfl_xor(ss, off);
  }
  float mean = s * (1.0f / 256.0f);
  float var  = ss * (1.0f / 256.0f) - mean * mean;
  float rstd = rsqrtf(var + 1e-5f);
#pragma unroll
  for (int j = 0; j < 8; ++j) {
    float4 gg = ((const float4*)(g2  + c8 * 32))[j];
    float4 bb = ((const float4*)(be2 + c8 * 32))[j];
    As[j*4+0][c8][r] = (x[j].x - mean) * rstd * gg.x + bb.x;
    As[j*4+1][c8][r] = (x[j].y - mean) * rstd * gg.y + bb.y;
    As[j*4+2][c8][r] = (x[j].z - mean) * rstd * gg.z + bb.z;
    As[j*4+3][c8][r] = (x[j].w - mean) * rstd * gg.w + bb.w;
  }
#pragma unroll
  for (int kb = 0; kb < 8; ++kb) {
    int k = kb * 32 + r;
    float4 b4 = *(const float4*)(w1 + (size_t)k * 1024 + n0 + c8 * 4);
    *(float4*)&Bs[k][c8 * 4] = b4;
  }
  if (blockIdx.x == 0) {                    // outb := mask*(X + b2)
    float mm = (smask[row] != 0) ? 0.0f : 1.0f;
#pragma unroll
    for (int j = 0; j < 8; ++j) {
      float4 b24 = ((const float4*)(b2 + c8 * 32))[j];
      float4 oi;
      oi.x = mm * (x[j].x + b24.x); oi.y = mm * (x[j].y + b24.y);
      oi.z = mm * (x[j].z + b24.z); oi.w = mm * (x[j].w + b24.w);
      *(float4*)&outb[(size_t)row * 256 + c8 * 32 + j * 4] = oi;
    }
  }
  __syncthreads();

  int tx = tid & 15, ty = tid >> 4;
  float acc[2][2] = {};
  for (int kcc = 0; kcc < 8; ++kcc) {
#pragma unroll
    for (int kk = 0; kk < 32; ++kk) {
      float2 av = *(const float2*)&As[kk][kcc][ty * 2];
      float2 bv = *(const float2*)&Bs[kcc * 32 + kk][tx * 2];
      acc[0][0] = fmaf(av.x, bv.x, acc[0][0]); acc[0][1] = fmaf(av.x, bv.y, acc[0][1]);
      acc[1][0] = fmaf(av.y, bv.x, acc[1][0]); acc[1][1] = fmaf(av.y, bv.y, acc[1][1]);
    }
  }

  int c0 = n0 + tx * 2;
#pragma unroll
  for (int i = 0; i < 2; ++i) {
    int m = m0 + ty * 2 + i;
    float2 rr;
    rr.x = fmaxf(acc[i][0] + b1[c0 + 0], 0.0f);
    rr.y = fmaxf(acc[i][1] + b1[c0 + 1], 0.0f);
    *(float2*)&H1[m * 1024 + c0] = rr;
  }
}

// =======================================================================
// full-stage 32x32 GEMM core for wo/ff2: A[m][k] tile transposed into
// At[K][34], B[k][n] tile into Bs[K][34]; single sync; K barrier-free iters.
// KPASS = K/32 (<=8).
// =======================================================================
template<int KPASS>
__device__ __forceinline__ void gemm_full32(
    const float* __restrict__ A, int lda,
    const float* __restrict__ Bw, int ldb,
    int kbeg, int m0, int n0,
    float* At /*[KPASS*32][34]*/, float* Bs /*[KPASS*32][34]*/,
    float acc[2][2])
{
  int tid = threadIdx.x;
  int r = tid >> 3, c8 = tid & 7;
#pragma unroll
  for (int kb = 0; kb < KPASS; ++kb) {
    int kl = kb * 32 + c8 * 4;
    float4 a4 = *(const float4*)(A + (size_t)(m0 + r) * lda + kbeg + kl);
    At[(kl + 0) * 34 + r] = a4.x;
    At[(kl + 1) * 34 + r] = a4.y;
    At[(kl + 2) * 34 + r] = a4.z;
    At[(kl + 3) * 34 + r] = a4.w;
    int k = kb * 32 + r;
    float4 b4 = *(const float4*)(Bw + (size_t)(kbeg + k) * ldb + n0 + c8 * 4);
    *(float4*)&Bs[k * 34 + c8 * 4] = b4;
  }
  __syncthreads();
  int tx = tid & 15, ty = tid >> 4;
  for (int kc = 0; kc < KPASS; ++kc) {
#pragma unroll
    for (int kk = 0; kk < 32; ++kk) {
      int k = kc * 32 + kk;
      float2 av = *(const float2*)&At[k * 34 + ty * 2];
      float2 bv = *(const float2*)&Bs[k * 34 + tx * 2];
      acc[0][0] = fmaf(av.x, bv.x, acc[0][0]); acc[0][1] = fmaf(av.x, bv.y, acc[0][1]);
      acc[1][0] = fmaf(av.y, bv.x, acc[1][0]); acc[1][1] = fmaf(av.y, bv.y, acc[1][1]);
    }
  }
}

// ---------- wo GEMM split-K=2, atomic into X : grid (8,16,2) ----------
__global__ __launch_bounds__(256, 2) void wo_kernel(
    const float* __restrict__ AO, const float* __restrict__ wo,
    float* __restrict__ X)
{
  __shared__ float At[128 * 34];
  __shared__ float Bs[128 * 34];
  int m0 = blockIdx.y * 32, n0 = blockIdx.x * 32;
  int kbeg = blockIdx.z * 128;
  float acc[2][2] = {};
  gemm_full32<4>(AO, 256, wo, 256, kbeg, m0, n0, At, Bs, acc);
  int tid = threadIdx.x, tx = tid & 15, ty = tid >> 4;
  int c0 = n0 + tx * 2;
#pragma unroll
  for (int i = 0; i < 2; ++i) {
    int m = m0 + ty * 2 + i;
    atomicAdd(&X[m * 256 + c0 + 0], acc[i][0]);
    atomicAdd(&X[m * 256 + c0 + 1], acc[i][1]);
  }
}

// ---------- FF2 split-K=4, masked atomic : grid (8,16,4) ----------
__global__ __launch_bounds__(256, 2) void ff2_kernel(
    const float* __restrict__ H1, const float* __restrict__ w2,
    const int* __restrict__ smask, float* __restrict__ outb)
{
  __shared__ float At[256 * 34];
  __shared__ float Bs[256 * 34];
  int m0 = blockIdx.y * 32, n0 = blockIdx.x * 32;
  int kbeg = blockIdx.z * 256;
  float acc[2][2] = {};
  gemm_full32<8>(H1, 1024, w2, 256, kbeg, m0, n0, At, Bs, acc);
  int tid = threadIdx.x, tx = tid & 15, ty = tid >> 4;
  int c0 = n0 + tx * 2;
#pragma unroll
  for (int i = 0; i < 2; ++i) {
    int m = m0 + ty * 2 + i;
    float mm = (smask[m] != 0) ? 0.0f : 1.0f;
    atomicAdd(&outb[m * 256 + c0 + 0], mm * acc[i][0]);
    atomicAdd(&outb[m * 256 + c0 + 1], mm * acc[i][1]);
  }
}

// ---------- attention: block = (b,h,8 s-rows), 256 thr; grid 512 ----------
__global__ __launch_bounds__(256) void attn_kernel(
    const float* __restrict__ Qb, const float* __restrict__ Kb, const float* __restrict__ Vb,
    const float* __restrict__ rpe, const int* __restrict__ tmask,
    const float* __restrict__ wrl, const float* __restrict__ brl,
    float* __restrict__ AO)
{
  __shared__ float Ks[256][32];
  __shared__ float Vt[32][260];
  __shared__ float ps[4][256];
  __shared__ float qs[8][32];
  __shared__ float wks[5][32];
  __shared__ float wvs[5][32];
  int bid = blockIdx.x;
  int b = bid >> 8, h = (bid >> 5) & 7, s0 = (bid & 31) << 3;
  int tid = threadIdx.x;
  const float* Kp = Kb + (size_t)(b * 8 + h) * 8192;
  const float* Vp = Vb + (size_t)(b * 8 + h) * 8192;
  {
    int t = tid;
    const float4* kr = (const float4*)(Kp + t * 32);
    const float4* vr = (const float4*)(Vp + t * 32);
    int sw = t & 7;
#pragma unroll
    for (int c = 0; c < 8; ++c) {
      float4 k4 = kr[c];
      *(float4*)&Ks[t][(c ^ sw) * 4] = k4;
    }
#pragma unroll
    for (int c = 0; c < 8; ++c) {
      float4 v4 = vr[c];
      Vt[c*4+0][t] = v4.x; Vt[c*4+1][t] = v4.y; Vt[c*4+2][t] = v4.z; Vt[c*4+3][t] = v4.w;
    }
  }
  if (tid < 160) {
    int j = tid >> 5, d = tid & 31;
    wks[j][d] = (j < 4) ? wrl[j * 512 + h * 32 + d]       : brl[h * 32 + d];
    wvs[j][d] = (j < 4) ? wrl[j * 512 + 256 + h * 32 + d] : brl[256 + h * 32 + d];
  }
  if (tid >= 192) {                    // 64 threads load the 8x32 Q tile
    int u = tid - 192;
    int rr2 = u >> 3, cc = u & 7;
    *(float4*)&qs[rr2][cc*4] =
        *(const float4*)&Qb[(b * 256 + s0 + rr2) * 256 + h * 32 + cc * 4];
  }
  __syncthreads();

  int w = tid >> 6, lane = tid & 63;
  int msk[4];
#pragma unroll
  for (int it = 0; it < 4; ++it) msk[it] = tmask[b * 256 + it * 64 + lane];

  for (int i = 0; i < 2; ++i) {
    int sl = w * 2 + i;
    int s = s0 + sl;
    float4 q4[8];
#pragma unroll
    for (int c = 0; c < 8; ++c) q4[c] = *(const float4*)&qs[sl][c * 4];
    float qw[4]; float qbr = 0.0f;
#pragma unroll
    for (int j = 0; j < 4; ++j) {
      float t0 = 0;
#pragma unroll
      for (int c = 0; c < 8; ++c) {
        float4 wv4 = *(const float4*)&wks[j][c * 4];
        t0 += q4[c].x*wv4.x + q4[c].y*wv4.y + q4[c].z*wv4.z + q4[c].w*wv4.w;
      }
      qw[j] = t0;
    }
#pragma unroll
    for (int c = 0; c < 8; ++c) {
      float4 wv4 = *(const float4*)&wks[4][c * 4];
      qbr += q4[c].x*wv4.x + q4[c].y*wv4.y + q4[c].z*wv4.z + q4[c].w*wv4.w;
    }
    const float4* rp4 = (const float4*)(rpe + (size_t)(b * 256 + s) * 1024);
    float sc[4]; float4 rr[4];
#pragma unroll
    for (int it = 0; it < 4; ++it) {
      int t = it * 64 + lane;
      int sw = t & 7;
      float sv = 0;
#pragma unroll
      for (int c = 0; c < 8; ++c) {
        float4 k4 = *(const float4*)&Ks[t][(c ^ sw) * 4];
        sv = fmaf(q4[c].x, k4.x, sv); sv = fmaf(q4[c].y, k4.y, sv);
        sv = fmaf(q4[c].z, k4.z, sv); sv = fmaf(q4[c].w, k4.w, sv);
      }
      float4 rv = rp4[t];
      rr[it] = rv;
      sv += rv.x*qw[0] + rv.y*qw[1] + rv.z*qw[2] + rv.w*qw[3] + qbr;
      if (msk[it] != 0) sv = NEG_INF;
      sc[it] = sv;
    }
    float mval = fmaxf(fmaxf(sc[0], sc[1]), fmaxf(sc[2], sc[3]));
#pragma unroll
    for (int off = 32; off >= 1; off >>= 1) mval = fmaxf(mval, __shfl_xor(mval, off));
    float p[4], lsum = 0;
#pragma unroll
    for (int it = 0; it < 4; ++it) { p[it] = __expf(sc[it] - mval); lsum += p[it]; }
    float wj0 = 0, wj1 = 0, wj2 = 0, wj3 = 0;
#pragma unroll
    for (int it = 0; it < 4; ++it) {
      wj0 = fmaf(p[it], rr[it].x, wj0);
      wj1 = fmaf(p[it], rr[it].y, wj1);
      wj2 = fmaf(p[it], rr[it].z, wj2);
      wj3 = fmaf(p[it], rr[it].w, wj3);
    }
#pragma unroll
    for (int off = 32; off >= 1; off >>= 1) {
      lsum += __shfl_xor(lsum, off);
      wj0 += __shfl_xor(wj0, off);
      wj1 += __shfl_xor(wj1, off);
      wj2 += __shfl_xor(wj2, off);
      wj3 += __shfl_xor(wj3, off);
    }
#pragma unroll
    for (int it = 0; it < 4; ++it) ps[w][it * 64 + lane] = p[it];
    int g = lane >> 5, d = lane & 31;
    float o = 0;
#pragma unroll
    for (int n = 0; n < 32; ++n) {
      int t = g * 128 + n * 4;
      float4 p4 = *(const float4*)&ps[w][t];
      float4 v4 = *(const float4*)&Vt[d][t];
      o += p4.x*v4.x + p4.y*v4.y + p4.z*v4.z + p4.w*v4.w;
    }
    o += __shfl_xor(o, 32);
    float corr = wj0 * wvs[0][d] + wj1 * wvs[1][d] + wj2 * wvs[2][d] + wj3 * wvs[3][d];
    float oval = (o + corr) / lsum + wvs[4][d];
    if (lane < 32) AO[(b * 256 + s) * 256 + h * 32 + d] = oval;
  }
}

extern "C" void kernel_launch(void* const* d_in, const int* in_sizes, int n_in,
                              void* d_out, int out_size, void* d_ws, size_t ws_size,
                              hipStream_t stream)
{
  const float* src  = (const float*)d_in[0];
  const float* tgt  = (const float*)d_in[1];
  const float* rpe  = (const float*)d_in[2];
  const int*   smask = (const int*)d_in[3];
  const int*   tmask = (const int*)d_in[4];
  const float* ln1g = (const float*)d_in[5];
  const float* ln1b = (const float*)d_in[6];
  const float* lntg = (const float*)d_in[7];
  const float* lntb = (const float*)d_in[8];
  const float* ln2g = (const float*)d_in[9];
  const float* ln2b = (const float*)d_in[10];
  const float* wq = (const float*)d_in[11];
  const float* bq = (const float*)d_in[12];
  const float* wk = (const float*)d_in[13];
  const float* bk = (const float*)d_in[14];
  const float* wv = (const float*)d_in[15];
  const float* bv = (const float*)d_in[16];
  const float* wo = (const float*)d_in[17];
  const float* bo = (const float*)d_in[18];
  const float* wr = (const float*)d_in[19];
  const float* br = (const float*)d_in[20];
  const float* w1 = (const float*)d_in[21];
  const float* b1 = (const float*)d_in[22];
  const float* w2 = (const float*)d_in[23];
  const float* b2 = (const float*)d_in[24];

  float* ws   = (float*)d_ws;
  float* Qb   = ws;
  float* Kb   = ws + 131072;
  float* Vb   = ws + 262144;
  float* AO   = ws + 393216;
  float* X    = ws + 524288;
  float* SRC1 = ws + 655360;
  float* H1   = ws + 786432;

  for (int l = 0; l < 2; ++l) {
    const float* srcin = l ? SRC1 : src;
    float* outb = l ? (float*)d_out : SRC1;
    qkv_ln_kernel<<<dim3(8, 16, 3), 256, 0, stream>>>(
        srcin, tgt, ln1g + l*256, ln1b + l*256, lntg + l*256, lntb + l*256,
        bo + l*256,
        wq + l*65536, wk + l*65536, wv + l*65536,
        bq + l*256, bk + l*256, bv + l*256,
        Qb, Kb, Vb, X);
    attn_kernel<<<512, 256, 0, stream>>>(Qb, Kb, Vb, rpe, tmask,
                                         wr + l*2048, br + l*512, AO);
    wo_kernel<<<dim3(8, 16, 2), 256, 0, stream>>>(AO, wo + l*65536, X);
    ff1_ln2_kernel<<<dim3(32, 16), 256, 0, stream>>>(
        X, ln2g + l*256, ln2b + l*256, b2 + l*256, smask,
        w1 + l*262144, b1 + l*1024, H1, outb);
    ff2_kernel<<<dim3(8, 16, 4), 256, 0, stream>>>(H1, w2 + l*262144, smask, outb);
  }
}